// Round 2
// baseline (3778.691 us; speedup 1.0000x reference)
//
#include <hip/hip_runtime.h>
#include <math.h>

#define Bn 16
#define Tn 2048
#define Cn 2048
#define HSn 256
#define SCALE 45.254833995939045f
#define NEG_BIG (-1e30f)

// ---------------------------------------------------------------------------
// Kernel 1: QKV projections.  X [M=B*T, C] @ W [C, HS] -> [M, HS], fp32.
// Tile 128(M) x 64(N), K-chunk 16, 256 threads, each thread 8x4 accum.
// ---------------------------------------------------------------------------
__global__ __launch_bounds__(256) void proj_kernel(
    const float* __restrict__ X, const float* __restrict__ Wk,
    const float* __restrict__ Wq, const float* __restrict__ Wv,
    float* __restrict__ K, float* __restrict__ Q, float* __restrict__ V)
{
    __shared__ float Xs[16][132];  // [k][m], transposed, padded
    __shared__ float Ws[16][68];   // [k][n], padded

    const float* W; float* O;
    switch (blockIdx.z) {
        case 0:  W = Wk; O = K; break;
        case 1:  W = Wq; O = Q; break;
        default: W = Wv; O = V; break;
    }

    const int tid = threadIdx.x;
    const int tx = tid & 15, ty = tid >> 4;
    const int m0 = blockIdx.x * 128;
    const int n0 = blockIdx.y * 64;

    float acc[8][4];
    #pragma unroll
    for (int r = 0; r < 8; ++r)
        #pragma unroll
        for (int c = 0; c < 4; ++c) acc[r][c] = 0.f;

    for (int k0 = 0; k0 < Cn; k0 += 16) {
        // stage X tile 128x16 (transpose into LDS), 2 float4 per thread
        #pragma unroll
        for (int p = 0; p < 2; ++p) {
            const int id  = tid * 2 + p;      // 0..511
            const int row = id >> 2;          // 0..127
            const int k4  = (id & 3) * 4;     // 0,4,8,12
            const float4 xv = *(const float4*)(X + (long)(m0 + row) * Cn + k0 + k4);
            Xs[k4+0][row] = xv.x; Xs[k4+1][row] = xv.y;
            Xs[k4+2][row] = xv.z; Xs[k4+3][row] = xv.w;
        }
        // stage W tile 16x64, 1 float4 per thread
        {
            const int row = tid >> 4;         // 0..15
            const int n4  = (tid & 15) * 4;   // 0..60
            *(float4*)&Ws[row][n4] = *(const float4*)(W + (long)(k0 + row) * HSn + n0 + n4);
        }
        __syncthreads();
        #pragma unroll
        for (int kk = 0; kk < 16; ++kk) {
            const float4 a0 = *(const float4*)&Xs[kk][ty * 8];
            const float4 a1 = *(const float4*)&Xs[kk][ty * 8 + 4];
            const float4 b0 = *(const float4*)&Ws[kk][tx * 4];
            const float a[8]  = {a0.x,a0.y,a0.z,a0.w,a1.x,a1.y,a1.z,a1.w};
            const float bb[4] = {b0.x,b0.y,b0.z,b0.w};
            #pragma unroll
            for (int r = 0; r < 8; ++r)
                #pragma unroll
                for (int c = 0; c < 4; ++c)
                    acc[r][c] = fmaf(a[r], bb[c], acc[r][c]);
        }
        __syncthreads();
    }
    #pragma unroll
    for (int r = 0; r < 8; ++r) {
        const float4 ov = make_float4(acc[r][0], acc[r][1], acc[r][2], acc[r][3]);
        *(float4*)(O + (long)(m0 + ty * 8 + r) * HSn + n0 + tx * 4) = ov;
    }
}

// ---------------------------------------------------------------------------
// score_tile: s[4][4] (i x j) = K[i0..i0+64) . Q[j0..j0+64) over h=256.
// 256 threads: ty -> 4 i rows, tx -> 4 j cols. LDS-staged in 8 chunks of 32 h.
// ---------------------------------------------------------------------------
__device__ __forceinline__ void score_tile(
    const float* __restrict__ Kb, const float* __restrict__ Qb,
    int i0, int j0, float (&Kt)[32][68], float (&Qt)[32][68],
    float (&s)[4][4], int tid, int tx, int ty)
{
    #pragma unroll
    for (int r = 0; r < 4; ++r)
        #pragma unroll
        for (int c = 0; c < 4; ++c) s[r][c] = 0.f;

    #pragma unroll 1
    for (int hc = 0; hc < 8; ++hc) {
        #pragma unroll
        for (int p = 0; p < 2; ++p) {
            const int id  = tid * 2 + p;     // 0..511
            const int row = id >> 3;         // 0..63
            const int h4  = (id & 7) * 4;    // 0..28
            const float4 kv = *(const float4*)(Kb + (long)(i0 + row) * HSn + hc * 32 + h4);
            Kt[h4+0][row] = kv.x; Kt[h4+1][row] = kv.y;
            Kt[h4+2][row] = kv.z; Kt[h4+3][row] = kv.w;
            const float4 qv = *(const float4*)(Qb + (long)(j0 + row) * HSn + hc * 32 + h4);
            Qt[h4+0][row] = qv.x; Qt[h4+1][row] = qv.y;
            Qt[h4+2][row] = qv.z; Qt[h4+3][row] = qv.w;
        }
        __syncthreads();
        #pragma unroll
        for (int h = 0; h < 32; ++h) {
            const float4 kv = *(const float4*)&Kt[h][ty * 4];
            const float4 qv = *(const float4*)&Qt[h][tx * 4];
            const float ka[4] = {kv.x,kv.y,kv.z,kv.w};
            const float qa[4] = {qv.x,qv.y,qv.z,qv.w};
            #pragma unroll
            for (int r = 0; r < 4; ++r)
                #pragma unroll
                for (int c = 0; c < 4; ++c)
                    s[r][c] = fmaf(ka[r], qa[c], s[r][c]);
        }
        __syncthreads();
    }
}

// ---------------------------------------------------------------------------
// Kernel 2: per-column softmax stats. Column j: m[j]=max_{i>=j} s, d[j]=sum exp.
// Grid (jt, b). Block owns 64 columns, loops i-tiles >= diagonal.
// ---------------------------------------------------------------------------
__global__ __launch_bounds__(256) void stats_kernel(
    const float* __restrict__ K, const float* __restrict__ Q,
    float* __restrict__ Ms, float* __restrict__ Rd)
{
    __shared__ float Kt[32][68], Qt[32][68];
    __shared__ float redm[64][17], redd[64][17];

    const int tid = threadIdx.x, tx = tid & 15, ty = tid >> 4;
    const int b = blockIdx.y, jt = blockIdx.x, j0 = jt * 64;
    const float* Kb = K + (long)b * Tn * HSn;
    const float* Qb = Q + (long)b * Tn * HSn;

    float mrun[4], drun[4];
    #pragma unroll
    for (int c = 0; c < 4; ++c) { mrun[c] = NEG_BIG; drun[c] = 0.f; }

    for (int it = jt; it < Tn / 64; ++it) {
        const int i0 = it * 64;
        float s[4][4];
        score_tile(Kb, Qb, i0, j0, Kt, Qt, s, tid, tx, ty);
        #pragma unroll
        for (int r = 0; r < 4; ++r) {
            const int i = i0 + ty * 4 + r;
            #pragma unroll
            for (int c = 0; c < 4; ++c) {
                const int j = j0 + tx * 4 + c;
                if (i >= j) {
                    const float sv = s[r][c] * SCALE;
                    const float mn = fmaxf(mrun[c], sv);
                    drun[c] = drun[c] * __expf(mrun[c] - mn) + __expf(sv - mn);
                    mrun[c] = mn;
                }
            }
        }
    }
    #pragma unroll
    for (int c = 0; c < 4; ++c) { redm[tx*4+c][ty] = mrun[c]; redd[tx*4+c][ty] = drun[c]; }
    __syncthreads();
    if (tid < 64) {
        float m = NEG_BIG;
        #pragma unroll
        for (int t = 0; t < 16; ++t) m = fmaxf(m, redm[tid][t]);
        float d = 0.f;
        #pragma unroll
        for (int t = 0; t < 16; ++t) d += redd[tid][t] * __expf(redm[tid][t] - m);
        Ms[(long)b * Tn + j0 + tid] = m;
        Rd[(long)b * Tn + j0 + tid] = 1.0f / d;
    }
}

// ---------------------------------------------------------------------------
// Kernel 3: output. Block owns O[i0..i0+64) x 256h; loops j-tiles <= i-tile,
// recomputes score tile, P = exp(s-m[j])/d[j], O += P @ V.
// Thread: 4 i rows (ty) x 16 h (4 segs of tx*4) -> 64 fp32 accums.
// ---------------------------------------------------------------------------
__global__ __launch_bounds__(256) void out_kernel(
    const float* __restrict__ K, const float* __restrict__ Q, const float* __restrict__ V,
    const float* __restrict__ Ms, const float* __restrict__ Rd, float* __restrict__ Out)
{
    __shared__ float Kt[32][68], Qt[32][68];
    __shared__ float Pl[64][68];
    __shared__ float Vl[16][260];

    const int tid = threadIdx.x, tx = tid & 15, ty = tid >> 4;
    const int b = blockIdx.y;
    const int it = gridDim.x - 1 - blockIdx.x;  // heaviest blocks launch first
    const int i0 = it * 64;
    const float* Kb = K + (long)b * Tn * HSn;
    const float* Qb = Q + (long)b * Tn * HSn;
    const float* Vb = V + (long)b * Tn * HSn;

    float o[4][16];
    #pragma unroll
    for (int r = 0; r < 4; ++r)
        #pragma unroll
        for (int u = 0; u < 16; ++u) o[r][u] = 0.f;

    for (int jt = 0; jt <= it; ++jt) {
        const int j0 = jt * 64;
        float s[4][4];
        score_tile(Kb, Qb, i0, j0, Kt, Qt, s, tid, tx, ty);

        float mj[4], rdj[4];
        #pragma unroll
        for (int c = 0; c < 4; ++c) {
            mj[c]  = Ms[(long)b * Tn + j0 + tx * 4 + c];
            rdj[c] = Rd[(long)b * Tn + j0 + tx * 4 + c];
        }
        #pragma unroll
        for (int r = 0; r < 4; ++r) {
            const int i = i0 + ty * 4 + r;
            #pragma unroll
            for (int c = 0; c < 4; ++c) {
                const int j = j0 + tx * 4 + c;
                float p = 0.f;
                if (i >= j) p = __expf(s[r][c] * SCALE - mj[c]) * rdj[c];
                Pl[ty * 4 + r][tx * 4 + c] = p;
            }
        }
        __syncthreads();

        #pragma unroll 1
        for (int vc = 0; vc < 4; ++vc) {
            // stage V chunk [16 j][256 h]
            {
                const int row = tid >> 4;            // 0..15
                #pragma unroll
                for (int kq = 0; kq < 4; ++kq) {
                    const int h = (tid & 15) * 4 + kq * 64;
                    *(float4*)&Vl[row][h] =
                        *(const float4*)(Vb + (long)(j0 + vc * 16 + row) * HSn + h);
                }
            }
            __syncthreads();
            #pragma unroll
            for (int jj = 0; jj < 16; ++jj) {
                float pr[4];
                #pragma unroll
                for (int r = 0; r < 4; ++r) pr[r] = Pl[ty * 4 + r][vc * 16 + jj];
                #pragma unroll
                for (int seg = 0; seg < 4; ++seg) {
                    const float4 vv = *(const float4*)&Vl[jj][seg * 64 + tx * 4];
                    #pragma unroll
                    for (int r = 0; r < 4; ++r) {
                        o[r][seg*4+0] = fmaf(pr[r], vv.x, o[r][seg*4+0]);
                        o[r][seg*4+1] = fmaf(pr[r], vv.y, o[r][seg*4+1]);
                        o[r][seg*4+2] = fmaf(pr[r], vv.z, o[r][seg*4+2]);
                        o[r][seg*4+3] = fmaf(pr[r], vv.w, o[r][seg*4+3]);
                    }
                }
            }
            __syncthreads();
        }
    }
    #pragma unroll
    for (int r = 0; r < 4; ++r) {
        #pragma unroll
        for (int seg = 0; seg < 4; ++seg) {
            const float4 ov = make_float4(o[r][seg*4+0], o[r][seg*4+1],
                                          o[r][seg*4+2], o[r][seg*4+3]);
            *(float4*)(Out + ((long)b * Tn + i0 + ty * 4 + r) * HSn + seg * 64 + tx * 4) = ov;
        }
    }
}

extern "C" void kernel_launch(void* const* d_in, const int* in_sizes, int n_in,
                              void* d_out, int out_size, void* d_ws, size_t ws_size,
                              hipStream_t stream) {
    const float* X  = (const float*)d_in[0];
    const float* Wk = (const float*)d_in[1];
    const float* Wq = (const float*)d_in[2];
    const float* Wv = (const float*)d_in[3];
    float* out = (float*)d_out;
    float* ws  = (float*)d_ws;

    const long nKQV = (long)Bn * Tn * HSn;   // 8,388,608 floats each
    float* K  = ws;
    float* Q  = ws + nKQV;
    float* V  = ws + 2 * nKQV;
    float* Ms = ws + 3 * nKQV;               // [B*T] column max
    float* Rd = Ms + (long)Bn * Tn;          // [B*T] 1/denominator
    // total ws need: 3*nKQV + 2*B*T floats ~= 96.3 MiB

    proj_kernel<<<dim3((Bn * Tn) / 128, HSn / 64, 3), 256, 0, stream>>>(
        X, Wk, Wq, Wv, K, Q, V);
    stats_kernel<<<dim3(Tn / 64, Bn), 256, 0, stream>>>(K, Q, Ms, Rd);
    out_kernel<<<dim3(Tn / 64, Bn), 256, 0, stream>>>(K, Q, V, Ms, Rd, out);
}

// Round 3
// 1907.680 us; speedup vs baseline: 1.9808x; 1.9808x over previous
//
#include <hip/hip_runtime.h>
#include <math.h>

#define Bn 16
#define Tn 2048
#define Cn 2048
#define HSn 256
#define SCALE 45.254833995939045f
#define NEG_BIG (-1e30f)
#define NT 16          // number of 128-tiles along T
#define NPAIR 136      // NT*(NT+1)/2

typedef __attribute__((ext_vector_type(8))) short bf16x8;
typedef __attribute__((ext_vector_type(4))) float f32x4;
typedef unsigned short u16;
typedef unsigned int u32;

__device__ __forceinline__ u16 bf16_rn(float f) {
    u32 u = __float_as_uint(f);
    u += 0x7fffu + ((u >> 16) & 1u);
    return (u16)(u >> 16);
}
__device__ __forceinline__ float bf16_rn_f(float f) {
    return __uint_as_float((u32)bf16_rn(f) << 16);
}

// ---------------------------------------------------------------------------
// Kernel 1: QKV projections (fp32 VALU core, validated in R2).
// Epilogue now writes split-bf16 Khi/Klo, Qhi/Qlo and bf16 V.
// ---------------------------------------------------------------------------
__global__ __launch_bounds__(256) void proj_kernel(
    const float* __restrict__ X, const float* __restrict__ Wk,
    const float* __restrict__ Wq, const float* __restrict__ Wv,
    u16* __restrict__ Khi, u16* __restrict__ Klo,
    u16* __restrict__ Qhi, u16* __restrict__ Qlo, u16* __restrict__ Vbf)
{
    __shared__ float Xs[16][132];  // [k][m], transposed, padded
    __shared__ float Ws[16][68];   // [k][n], padded

    const float* W;
    switch (blockIdx.z) {
        case 0:  W = Wk; break;
        case 1:  W = Wq; break;
        default: W = Wv; break;
    }

    const int tid = threadIdx.x;
    const int tx = tid & 15, ty = tid >> 4;
    const int m0 = blockIdx.x * 128;
    const int n0 = blockIdx.y * 64;

    float acc[8][4];
    #pragma unroll
    for (int r = 0; r < 8; ++r)
        #pragma unroll
        for (int c = 0; c < 4; ++c) acc[r][c] = 0.f;

    for (int k0 = 0; k0 < Cn; k0 += 16) {
        #pragma unroll
        for (int p = 0; p < 2; ++p) {
            const int id  = tid * 2 + p;      // 0..511
            const int row = id >> 2;          // 0..127
            const int k4  = (id & 3) * 4;     // 0,4,8,12
            const float4 xv = *(const float4*)(X + (long)(m0 + row) * Cn + k0 + k4);
            Xs[k4+0][row] = xv.x; Xs[k4+1][row] = xv.y;
            Xs[k4+2][row] = xv.z; Xs[k4+3][row] = xv.w;
        }
        {
            const int row = tid >> 4;         // 0..15
            const int n4  = (tid & 15) * 4;   // 0..60
            *(float4*)&Ws[row][n4] = *(const float4*)(W + (long)(k0 + row) * HSn + n0 + n4);
        }
        __syncthreads();
        #pragma unroll
        for (int kk = 0; kk < 16; ++kk) {
            const float4 a0 = *(const float4*)&Xs[kk][ty * 8];
            const float4 a1 = *(const float4*)&Xs[kk][ty * 8 + 4];
            const float4 b0 = *(const float4*)&Ws[kk][tx * 4];
            const float a[8]  = {a0.x,a0.y,a0.z,a0.w,a1.x,a1.y,a1.z,a1.w};
            const float bb[4] = {b0.x,b0.y,b0.z,b0.w};
            #pragma unroll
            for (int r = 0; r < 8; ++r)
                #pragma unroll
                for (int c = 0; c < 4; ++c)
                    acc[r][c] = fmaf(a[r], bb[c], acc[r][c]);
        }
        __syncthreads();
    }

    if (blockIdx.z == 2) {
        #pragma unroll
        for (int r = 0; r < 8; ++r) {
            ushort4 o;
            o.x = bf16_rn(acc[r][0]); o.y = bf16_rn(acc[r][1]);
            o.z = bf16_rn(acc[r][2]); o.w = bf16_rn(acc[r][3]);
            *(ushort4*)(Vbf + (long)(m0 + ty * 8 + r) * HSn + n0 + tx * 4) = o;
        }
    } else {
        u16* Ohi = (blockIdx.z == 0) ? Khi : Qhi;
        u16* Olo = (blockIdx.z == 0) ? Klo : Qlo;
        #pragma unroll
        for (int r = 0; r < 8; ++r) {
            ushort4 h4, l4;
            #pragma unroll
            for (int c = 0; c < 4; ++c) {
                const float f = acc[r][c];
                const u32 u = __float_as_uint(f);
                const u16 hb = (u16)(u >> 16);                    // truncate -> hi
                const float fh = __uint_as_float(u & 0xffff0000u);
                const float fl = f - fh;                          // exact residual
                const u16 lb = (u16)(__float_as_uint(fl) >> 16);  // truncate -> lo
                ((u16*)&h4)[c] = hb;
                ((u16*)&l4)[c] = lb;
            }
            const long off = (long)(m0 + ty * 8 + r) * HSn + n0 + tx * 4;
            *(ushort4*)(Ohi + off) = h4;
            *(ushort4*)(Olo + off) = l4;
        }
    }
}

// ---------------------------------------------------------------------------
// Shared: 128x128 score tile via split-bf16 MFMA.
// S[i][j] = sum_h K[i][h]*Q[j][h], K=Khi+Klo, Q=Qhi+Qlo (lo*lo dropped).
// 4 waves; wave (wm,wn) owns a 64x64 quadrant as 4x4 grid of 16x16 MFMAs.
// LDS tiles stored frag-native: chunk*1024B + lane*16B -> conflict-free b128.
// A-frag: lane l holds M[m = l&15][k = (l>>4)*8 + u]; same for B (n = l&15).
// C/D: col = l&15, row = (l>>4)*4 + reg.
// ---------------------------------------------------------------------------
__device__ __forceinline__ void score_tile_mfma(
    const u16* __restrict__ Khi, const u16* __restrict__ Klo,
    const u16* __restrict__ Qhi, const u16* __restrict__ Qlo,
    long base, int i0, int j0,
    u16* Abuf, u16* Bbuf, f32x4 (&acc)[4][4], int tid)
{
    const int l = tid & 63, w = tid >> 6;
    const int wm = w & 1, wn = w >> 1;
    const int lrow = l & 15, lk8 = (l >> 4) << 3;

    #pragma unroll
    for (int a = 0; a < 4; ++a)
        #pragma unroll
        for (int bb = 0; bb < 4; ++bb)
            #pragma unroll
            for (int r = 0; r < 4; ++r) acc[a][bb][r] = 0.f;

    for (int ks = 0; ks < 8; ++ks) {
        const int h0 = ks * 32;
        // stage 32 frag-chunks (16 K-side, 16 Q-side); this wave does 8
        #pragma unroll
        for (int q = 0; q < 8; ++q) {
            const int c    = (w << 3) | q;
            const int side = c >> 4;          // 0:K(A) 1:Q(B)
            const int cc   = c & 15;
            const int half = cc & 1;          // 0:hi 1:lo
            const int mt   = cc >> 1;         // 0..7 -> 16-row group
            const u16* src = side ? (half ? Qlo : Qhi) : (half ? Klo : Khi);
            const int row  = (side ? j0 : i0) + mt * 16 + lrow;
            const uint4 v  = *(const uint4*)(src + base + (long)row * HSn + h0 + lk8);
            u16* dst = (side ? Bbuf : Abuf) + cc * 512 + l * 8;
            *(uint4*)dst = v;
        }
        __syncthreads();
        bf16x8 bh[4], bl[4];
        #pragma unroll
        for (int nt = 0; nt < 4; ++nt) {
            const int c2 = (wn * 4 + nt) * 2;
            bh[nt] = *(const bf16x8*)(Bbuf + (c2    ) * 512 + l * 8);
            bl[nt] = *(const bf16x8*)(Bbuf + (c2 + 1) * 512 + l * 8);
        }
        #pragma unroll
        for (int mt = 0; mt < 4; ++mt) {
            const int c2 = (wm * 4 + mt) * 2;
            const bf16x8 ah = *(const bf16x8*)(Abuf + (c2    ) * 512 + l * 8);
            const bf16x8 al = *(const bf16x8*)(Abuf + (c2 + 1) * 512 + l * 8);
            #pragma unroll
            for (int nt = 0; nt < 4; ++nt) {
                acc[mt][nt] = __builtin_amdgcn_mfma_f32_16x16x32_bf16(ah, bh[nt], acc[mt][nt], 0, 0, 0);
                acc[mt][nt] = __builtin_amdgcn_mfma_f32_16x16x32_bf16(ah, bl[nt], acc[mt][nt], 0, 0, 0);
                acc[mt][nt] = __builtin_amdgcn_mfma_f32_16x16x32_bf16(al, bh[nt], acc[mt][nt], 0, 0, 0);
            }
        }
        __syncthreads();
    }
}

__device__ __forceinline__ void pair_from_p(int p, int& it, int& jt) {
    it = (int)((sqrtf(8.f * (float)p + 1.f) - 1.f) * 0.5f);
    while ((it + 1) * (it + 2) / 2 <= p) ++it;
    while (it * (it + 1) / 2 > p) --it;
    jt = p - it * (it + 1) / 2;
}

// ---------------------------------------------------------------------------
// Kernel 2a: per-(pair, column) partial softmax stats (m, d), bf16.
// d is computed against bf16-rounded m -> consistent by shift-invariance.
// ---------------------------------------------------------------------------
__global__ __launch_bounds__(256) void stats1_kernel(
    const u16* __restrict__ Khi, const u16* __restrict__ Klo,
    const u16* __restrict__ Qhi, const u16* __restrict__ Qlo,
    u16* __restrict__ Pm, u16* __restrict__ Pd)
{
    __shared__ u16 Abuf[8192], Bbuf[8192];
    __shared__ float redm[2][128], redd[2][128];

    const int tid = threadIdx.x, l = tid & 63, w = tid >> 6;
    const int wm = w & 1, wn = w >> 1;
    const int b = blockIdx.y;
    int it, jt; pair_from_p(blockIdx.x, it, jt);
    const long base = (long)b * Tn * HSn;

    f32x4 acc[4][4];
    score_tile_mfma(Khi, Klo, Qhi, Qlo, base, it * 128, jt * 128, Abuf, Bbuf, acc, tid);

    const int rquad = (l >> 4) * 4, col = l & 15;
    #pragma unroll
    for (int nt = 0; nt < 4; ++nt) {
        const int j = jt * 128 + wn * 64 + nt * 16 + col;
        float m = NEG_BIG;
        #pragma unroll
        for (int mt = 0; mt < 4; ++mt)
            #pragma unroll
            for (int r = 0; r < 4; ++r) {
                const int i = it * 128 + wm * 64 + mt * 16 + rquad + r;
                const float sv = (i >= j) ? acc[mt][nt][r] * SCALE : NEG_BIG;
                acc[mt][nt][r] = sv;
                m = fmaxf(m, sv);
            }
        m = fmaxf(m, __shfl_xor(m, 16));
        m = fmaxf(m, __shfl_xor(m, 32));
        float d = 0.f;
        #pragma unroll
        for (int mt = 0; mt < 4; ++mt)
            #pragma unroll
            for (int r = 0; r < 4; ++r)
                d += __expf(acc[mt][nt][r] - m);
        d += __shfl_xor(d, 16);
        d += __shfl_xor(d, 32);
        if (l < 16) {
            redm[wm][wn * 64 + nt * 16 + l] = m;
            redd[wm][wn * 64 + nt * 16 + l] = d;
        }
    }
    __syncthreads();
    if (tid < 128) {
        const float m0 = redm[0][tid], m1 = redm[1][tid];
        const float d0 = redd[0][tid], d1 = redd[1][tid];
        const float M = fmaxf(m0, m1);
        float D = d0 * __expf(m0 - M) + d1 * __expf(m1 - M);
        const float Mb = bf16_rn_f(M);
        D *= __expf(M - Mb);      // rebase to the rounded max we will store
        const long idx = ((long)b * NPAIR + blockIdx.x) * 128 + tid;
        Pm[idx] = (u16)(__float_as_uint(Mb) >> 16);
        Pd[idx] = bf16_rn(D);
    }
}

// ---------------------------------------------------------------------------
// Kernel 2b: merge partials over i-tiles -> Ms (column max), Rd (1/denominator)
// ---------------------------------------------------------------------------
__global__ __launch_bounds__(128) void stats2_kernel(
    const u16* __restrict__ Pm, const u16* __restrict__ Pd,
    float* __restrict__ Ms, float* __restrict__ Rd)
{
    const int b = blockIdx.y, jt = blockIdx.x, jl = threadIdx.x;  // 128 threads
    float M = NEG_BIG, D = 0.f;
    for (int it = jt; it < NT; ++it) {
        const int p = it * (it + 1) / 2 + jt;
        const long idx = ((long)b * NPAIR + p) * 128 + jl;
        const float m = __uint_as_float((u32)Pm[idx] << 16);
        const float d = __uint_as_float((u32)Pd[idx] << 16);
        const float Mn = fmaxf(M, m);
        D = D * __expf(M - Mn) + d * __expf(m - Mn);
        M = Mn;
    }
    Ms[(long)b * Tn + jt * 128 + jl] = M;
    Rd[(long)b * Tn + jt * 128 + jl] = 1.f / D;
}

// ---------------------------------------------------------------------------
// Kernel 3: per-pair output partials. Recompute scores, P = exp(s-m_j)*rd_j,
// P -> LDS (bf16, A-layout-readable), V-tile transposed to LDS, P@V via MFMA,
// fp32 atomicAdd into zeroed Out.
// LDS: u_lds[0..17407] = Pf[128][136] (score Abuf/Bbuf overlap here, dead by
// then), u_lds[17408..34815] = Vt[128][136] (per h-half pass). 69.6 KB total.
// ---------------------------------------------------------------------------
__global__ __launch_bounds__(256) void out_kernel(
    const u16* __restrict__ Khi, const u16* __restrict__ Klo,
    const u16* __restrict__ Qhi, const u16* __restrict__ Qlo,
    const u16* __restrict__ Vbf, const float* __restrict__ Ms,
    const float* __restrict__ Rd, float* __restrict__ Out)
{
    __shared__ u16 u_lds[34816];
    u16* Abuf = u_lds;
    u16* Bbuf = u_lds + 8192;
    u16* Pf   = u_lds;           // [128][136] bf16
    u16* Vt   = u_lds + 17408;   // [128][136] bf16 (h-major)

    const int tid = threadIdx.x, l = tid & 63, w = tid >> 6;
    const int wm = w & 1, wn = w >> 1;
    const int b = blockIdx.y;
    int it, jt; pair_from_p(blockIdx.x, it, jt);
    const long base = (long)b * Tn * HSn;

    f32x4 acc[4][4];
    score_tile_mfma(Khi, Klo, Qhi, Qlo, base, it * 128, jt * 128, Abuf, Bbuf, acc, tid);

    const int rquad = (l >> 4) * 4, col = l & 15;
    float mj[4], rj[4];
    #pragma unroll
    for (int nt = 0; nt < 4; ++nt) {
        const int j = jt * 128 + wn * 64 + nt * 16 + col;
        mj[nt] = Ms[(long)b * Tn + j];
        rj[nt] = Rd[(long)b * Tn + j];
    }
    // P tile -> LDS bf16 (scores LDS is dead; all waves passed final barrier)
    #pragma unroll
    for (int nt = 0; nt < 4; ++nt) {
        const int j = jt * 128 + wn * 64 + nt * 16 + col;
        #pragma unroll
        for (int mt = 0; mt < 4; ++mt)
            #pragma unroll
            for (int r = 0; r < 4; ++r) {
                const int i = it * 128 + wm * 64 + mt * 16 + rquad + r;
                const float pv = (i >= j)
                    ? __expf(acc[mt][nt][r] * SCALE - mj[nt]) * rj[nt] : 0.f;
                Pf[(wm * 64 + mt * 16 + rquad + r) * 136 + wn * 64 + nt * 16 + col]
                    = bf16_rn(pv);
            }
    }

    const int lrow = l & 15, lk8 = (l >> 4) << 3;
    for (int ph = 0; ph < 2; ++ph) {
        __syncthreads();  // Pf ready (ph=0) / previous pass reads done (ph=1)
        // stage Vt[h 0..127][j 0..127] for h-half ph (transposed)
        {
            const int jj = tid & 127, hs = (tid >> 7) * 64;
            const long vbase = ((long)b * Tn + jt * 128 + jj) * HSn + ph * 128 + hs;
            #pragma unroll
            for (int qq = 0; qq < 8; ++qq) {
                union { uint4 v; u16 s[8]; } uu;
                uu.v = *(const uint4*)(Vbf + vbase + qq * 8);
                #pragma unroll
                for (int e = 0; e < 8; ++e)
                    Vt[(hs + qq * 8 + e) * 136 + jj] = uu.s[e];
            }
        }
        __syncthreads();

        f32x4 o[4][4];
        #pragma unroll
        for (int a = 0; a < 4; ++a)
            #pragma unroll
            for (int bb = 0; bb < 4; ++bb)
                #pragma unroll
                for (int r = 0; r < 4; ++r) o[a][bb][r] = 0.f;

        #pragma unroll
        for (int kj = 0; kj < 4; ++kj) {
            bf16x8 aP[4];
            #pragma unroll
            for (int mt = 0; mt < 4; ++mt)
                aP[mt] = *(const bf16x8*)(Pf + (wm * 64 + mt * 16 + lrow) * 136 + kj * 32 + lk8);
            #pragma unroll
            for (int nt = 0; nt < 4; ++nt) {
                const bf16x8 bV = *(const bf16x8*)(Vt + (wn * 64 + nt * 16 + lrow) * 136 + kj * 32 + lk8);
                #pragma unroll
                for (int mt = 0; mt < 4; ++mt)
                    o[mt][nt] = __builtin_amdgcn_mfma_f32_16x16x32_bf16(aP[mt], bV, o[mt][nt], 0, 0, 0);
            }
        }
        #pragma unroll
        for (int mt = 0; mt < 4; ++mt)
            #pragma unroll
            for (int nt = 0; nt < 4; ++nt)
                #pragma unroll
                for (int r = 0; r < 4; ++r) {
                    const int i = it * 128 + wm * 64 + mt * 16 + rquad + r;
                    const int h = ph * 128 + wn * 64 + nt * 16 + col;
                    atomicAdd(&Out[((long)b * Tn + i) * HSn + h], o[mt][nt][r]);
                }
    }
}

extern "C" void kernel_launch(void* const* d_in, const int* in_sizes, int n_in,
                              void* d_out, int out_size, void* d_ws, size_t ws_size,
                              hipStream_t stream) {
    const float* X  = (const float*)d_in[0];
    const float* Wk = (const float*)d_in[1];
    const float* Wq = (const float*)d_in[2];
    const float* Wv = (const float*)d_in[3];

    const long nE = (long)Bn * Tn * HSn;          // 8,388,608 elements
    u16* Khi = (u16*)d_ws;
    u16* Klo = Khi + nE;
    u16* Qhi = Khi + 2 * nE;
    u16* Qlo = Khi + 3 * nE;
    u16* Vbf = Khi + 4 * nE;
    u16* Pm  = Khi + 5 * nE;                      // [B][NPAIR][128] bf16
    u16* Pd  = Pm + (long)Bn * NPAIR * 128;
    float* Ms = (float*)(Pd + (long)Bn * NPAIR * 128);
    float* Rd = Ms + (long)Bn * Tn;
    // total ws: 5*nE*2B + 2*B*136*128*2B + 2*B*T*4B  ~= 81.3 MiB

    proj_kernel<<<dim3((Bn * Tn) / 128, HSn / 64, 3), 256, 0, stream>>>(
        X, Wk, Wq, Wv, Khi, Klo, Qhi, Qlo, Vbf);
    stats1_kernel<<<dim3(NPAIR, Bn), 256, 0, stream>>>(Khi, Klo, Qhi, Qlo, Pm, Pd);
    stats2_kernel<<<dim3(NT, Bn), 128, 0, stream>>>(Pm, Pd, Ms, Rd);
    hipMemsetAsync(d_out, 0, (size_t)out_size * sizeof(float), stream);
    out_kernel<<<dim3(NPAIR, Bn), 256, 0, stream>>>(Khi, Klo, Qhi, Qlo, Vbf, Ms, Rd,
                                                    (float*)d_out);
}

// Round 4
// 1435.344 us; speedup vs baseline: 2.6326x; 1.3291x over previous
//
#include <hip/hip_runtime.h>
#include <math.h>

#define Bn 16
#define Tn 2048
#define Cn 2048
#define HSn 256
#define SCALE 45.254833995939045f
#define NEG_BIG (-1e30f)
#define NT 16          // number of 128-tiles along T
#define NPAIR 136      // NT*(NT+1)/2
#define WN 524288      // Cn*HSn, elems per W matrix

typedef __attribute__((ext_vector_type(8))) short bf16x8;
typedef __attribute__((ext_vector_type(4))) float f32x4;
typedef unsigned short u16;
typedef unsigned int u32;

__device__ __forceinline__ u16 bf16_rn(float f) {
    u32 u = __float_as_uint(f);
    u += 0x7fffu + ((u >> 16) & 1u);
    return (u16)(u >> 16);
}
__device__ __forceinline__ float bf16_rn_f(float f) {
    return __uint_as_float((u32)bf16_rn(f) << 16);
}

// ---------------------------------------------------------------------------
// Kernel 0: split W matrices into transposed bf16 hi/lo: Wt[mat][n][k].
// Transposed layout makes the B-side of the projection GEMM stage exactly
// like the (validated) A-side frag-native pattern. 6 MB total, L2-resident.
// ---------------------------------------------------------------------------
__global__ __launch_bounds__(256) void split_w_kernel(
    const float* __restrict__ Wk, const float* __restrict__ Wq,
    const float* __restrict__ Wv, u16* __restrict__ Wt)
{
    const int n = threadIdx.x, k = blockIdx.x, mat = blockIdx.y;
    const float* src = (mat == 0) ? Wk : (mat == 1) ? Wq : Wv;
    const float f = src[(long)k * HSn + n];
    const u32 u = __float_as_uint(f);
    const u16 hb = (u16)(u >> 16);                 // truncate -> hi
    const float fh = __uint_as_float(u & 0xffff0000u);
    const u16 lb = bf16_rn(f - fh);                // round residual -> lo
    u16* base = Wt + (long)mat * 2 * WN;
    base[(long)n * Cn + k] = hb;
    base[WN + (long)n * Cn + k] = lb;
}

// ---------------------------------------------------------------------------
// Kernel 1: QKV projections via split-bf16 MFMA.
// z=0: K (3 products), z=1: Q (3 products), z=2: V (1 product, hi*hi).
// 128x128 output tile, BK=32, 4 waves as 2x2 quadrants of 4x4 16x16 MFMAs.
// X fp32 is split into bf16 hi/lo on the fly while staging to LDS
// (frag-native layout: chunk*1024B + lane*16B -> conflict-free ds_read_b128).
// ---------------------------------------------------------------------------
__global__ __launch_bounds__(256) void projm_kernel(
    const float* __restrict__ X, const u16* __restrict__ Wt,
    u16* __restrict__ Khi, u16* __restrict__ Klo,
    u16* __restrict__ Qhi, u16* __restrict__ Qlo, u16* __restrict__ Vbf)
{
    __shared__ u16 Ahi[4096], Alo[4096], Bhi[4096], Blo[4096];  // 32 KB

    const int tid = threadIdx.x, l = tid & 63, w = tid >> 6;
    const int wm = w & 1, wn = w >> 1;
    const int z = blockIdx.z;
    const int m0 = blockIdx.x * 128, n0 = blockIdx.y * 128;
    const u16* Wthi = Wt + (long)z * 2 * WN;
    const u16* Wtlo = Wthi + WN;

    f32x4 acc[4][4];
    #pragma unroll
    for (int a = 0; a < 4; ++a)
        #pragma unroll
        for (int bb = 0; bb < 4; ++bb)
            #pragma unroll
            for (int r = 0; r < 4; ++r) acc[a][bb][r] = 0.f;

    #pragma unroll 1
    for (int k0 = 0; k0 < Cn; k0 += 32) {
        // --- stage X tile 128x32 fp32 -> Ahi/Alo bf16 (frag-native) ---
        #pragma unroll
        for (int p = 0; p < 4; ++p) {
            const int idx4 = p * 256 + tid;     // 0..1023
            const int row  = idx4 >> 3;         // 0..127
            const int kk4  = (idx4 & 7) * 4;    // 0,4,...,28
            const float4 xv = *(const float4*)(X + (long)(m0 + row) * Cn + k0 + kk4);
            const float xf[4] = {xv.x, xv.y, xv.z, xv.w};
            ushort4 h4, l4;
            #pragma unroll
            for (int c = 0; c < 4; ++c) {
                const u32 u = __float_as_uint(xf[c]);
                ((u16*)&h4)[c] = (u16)(u >> 16);
                const float fh = __uint_as_float(u & 0xffff0000u);
                ((u16*)&l4)[c] = bf16_rn(xf[c] - fh);
            }
            // frag pos: lane = (row&15) | ((k>>3)<<4), elem = k&7
            const int off = (row >> 4) * 512 + (((row & 15) | ((kk4 >> 3) << 4)) * 8) + (kk4 & 7);
            *(ushort4*)(Ahi + off) = h4;
            if (z != 2) *(ushort4*)(Alo + off) = l4;
        }
        // --- stage Wt tile 128x32 bf16 hi/lo (already frag-orderable) ---
        #pragma unroll
        for (int p = 0; p < 4; ++p) {
            const int c = p * 4 + w;            // 0..15 (8 hi + 8 lo chunks)
            const int half = c >> 3, cc = c & 7;
            if (half == 0 || z != 2) {
                const u16* src = half ? Wtlo : Wthi;
                const int nrow = n0 + cc * 16 + (l & 15);
                const long ga = (long)nrow * Cn + k0 + (l >> 4) * 8;
                *(uint4*)((half ? Blo : Bhi) + cc * 512 + l * 8) = *(const uint4*)(src + ga);
            }
        }
        __syncthreads();
        bf16x8 bh[4], bl[4];
        #pragma unroll
        for (int nt = 0; nt < 4; ++nt) {
            bh[nt] = *(const bf16x8*)(Bhi + (wn * 4 + nt) * 512 + l * 8);
            if (z != 2) bl[nt] = *(const bf16x8*)(Blo + (wn * 4 + nt) * 512 + l * 8);
        }
        #pragma unroll
        for (int mt = 0; mt < 4; ++mt) {
            const bf16x8 ah = *(const bf16x8*)(Ahi + (wm * 4 + mt) * 512 + l * 8);
            if (z != 2) {
                const bf16x8 al = *(const bf16x8*)(Alo + (wm * 4 + mt) * 512 + l * 8);
                #pragma unroll
                for (int nt = 0; nt < 4; ++nt) {
                    acc[mt][nt] = __builtin_amdgcn_mfma_f32_16x16x32_bf16(ah, bh[nt], acc[mt][nt], 0, 0, 0);
                    acc[mt][nt] = __builtin_amdgcn_mfma_f32_16x16x32_bf16(ah, bl[nt], acc[mt][nt], 0, 0, 0);
                    acc[mt][nt] = __builtin_amdgcn_mfma_f32_16x16x32_bf16(al, bh[nt], acc[mt][nt], 0, 0, 0);
                }
            } else {
                #pragma unroll
                for (int nt = 0; nt < 4; ++nt)
                    acc[mt][nt] = __builtin_amdgcn_mfma_f32_16x16x32_bf16(ah, bh[nt], acc[mt][nt], 0, 0, 0);
            }
        }
        __syncthreads();
    }

    // --- epilogue: C/D layout col=l&15, row=(l>>4)*4+r ---
    const int quad = (l >> 4) * 4, col = l & 15;
    if (z == 2) {
        #pragma unroll
        for (int mt = 0; mt < 4; ++mt)
            #pragma unroll
            for (int nt = 0; nt < 4; ++nt)
                #pragma unroll
                for (int r = 0; r < 4; ++r) {
                    const long i = m0 + wm * 64 + mt * 16 + quad + r;
                    const int  j = n0 + wn * 64 + nt * 16 + col;
                    Vbf[i * HSn + j] = bf16_rn(acc[mt][nt][r]);
                }
    } else {
        u16* Ohi = z ? Qhi : Khi;
        u16* Olo = z ? Qlo : Klo;
        #pragma unroll
        for (int mt = 0; mt < 4; ++mt)
            #pragma unroll
            for (int nt = 0; nt < 4; ++nt)
                #pragma unroll
                for (int r = 0; r < 4; ++r) {
                    const float f = acc[mt][nt][r];
                    const u32 u = __float_as_uint(f);
                    const u16 hb = (u16)(u >> 16);
                    const float fh = __uint_as_float(u & 0xffff0000u);
                    const u16 lb = bf16_rn(f - fh);
                    const long i = m0 + wm * 64 + mt * 16 + quad + r;
                    const int  j = n0 + wn * 64 + nt * 16 + col;
                    Ohi[i * HSn + j] = hb;
                    Olo[i * HSn + j] = lb;
                }
    }
}

// ---------------------------------------------------------------------------
// Shared: 128x128 score tile via split-bf16 MFMA (validated R3).
// ---------------------------------------------------------------------------
__device__ __forceinline__ void score_tile_mfma(
    const u16* __restrict__ Khi, const u16* __restrict__ Klo,
    const u16* __restrict__ Qhi, const u16* __restrict__ Qlo,
    long base, int i0, int j0,
    u16* Abuf, u16* Bbuf, f32x4 (&acc)[4][4], int tid)
{
    const int l = tid & 63, w = tid >> 6;
    const int wm = w & 1, wn = w >> 1;
    const int lrow = l & 15, lk8 = (l >> 4) << 3;

    #pragma unroll
    for (int a = 0; a < 4; ++a)
        #pragma unroll
        for (int bb = 0; bb < 4; ++bb)
            #pragma unroll
            for (int r = 0; r < 4; ++r) acc[a][bb][r] = 0.f;

    for (int ks = 0; ks < 8; ++ks) {
        const int h0 = ks * 32;
        #pragma unroll
        for (int q = 0; q < 8; ++q) {
            const int c    = (w << 3) | q;
            const int side = c >> 4;          // 0:K(A) 1:Q(B)
            const int cc   = c & 15;
            const int half = cc & 1;          // 0:hi 1:lo
            const int mt   = cc >> 1;         // 0..7 -> 16-row group
            const u16* src = side ? (half ? Qlo : Qhi) : (half ? Klo : Khi);
            const int row  = (side ? j0 : i0) + mt * 16 + lrow;
            const uint4 v  = *(const uint4*)(src + base + (long)row * HSn + h0 + lk8);
            u16* dst = (side ? Bbuf : Abuf) + cc * 512 + l * 8;
            *(uint4*)dst = v;
        }
        __syncthreads();
        bf16x8 bh[4], bl[4];
        #pragma unroll
        for (int nt = 0; nt < 4; ++nt) {
            const int c2 = (wn * 4 + nt) * 2;
            bh[nt] = *(const bf16x8*)(Bbuf + (c2    ) * 512 + l * 8);
            bl[nt] = *(const bf16x8*)(Bbuf + (c2 + 1) * 512 + l * 8);
        }
        #pragma unroll
        for (int mt = 0; mt < 4; ++mt) {
            const int c2 = (wm * 4 + mt) * 2;
            const bf16x8 ah = *(const bf16x8*)(Abuf + (c2    ) * 512 + l * 8);
            const bf16x8 al = *(const bf16x8*)(Abuf + (c2 + 1) * 512 + l * 8);
            #pragma unroll
            for (int nt = 0; nt < 4; ++nt) {
                acc[mt][nt] = __builtin_amdgcn_mfma_f32_16x16x32_bf16(ah, bh[nt], acc[mt][nt], 0, 0, 0);
                acc[mt][nt] = __builtin_amdgcn_mfma_f32_16x16x32_bf16(ah, bl[nt], acc[mt][nt], 0, 0, 0);
                acc[mt][nt] = __builtin_amdgcn_mfma_f32_16x16x32_bf16(al, bh[nt], acc[mt][nt], 0, 0, 0);
            }
        }
        __syncthreads();
    }
}

__device__ __forceinline__ void pair_from_p(int p, int& it, int& jt) {
    it = (int)((sqrtf(8.f * (float)p + 1.f) - 1.f) * 0.5f);
    while ((it + 1) * (it + 2) / 2 <= p) ++it;
    while (it * (it + 1) / 2 > p) --it;
    jt = p - it * (it + 1) / 2;
}

// ---------------------------------------------------------------------------
// Kernel 2a: per-(pair, column) partial softmax stats (m, d), bf16.
// ---------------------------------------------------------------------------
__global__ __launch_bounds__(256) void stats1_kernel(
    const u16* __restrict__ Khi, const u16* __restrict__ Klo,
    const u16* __restrict__ Qhi, const u16* __restrict__ Qlo,
    u16* __restrict__ Pm, u16* __restrict__ Pd)
{
    __shared__ u16 Abuf[8192], Bbuf[8192];
    __shared__ float redm[2][128], redd[2][128];

    const int tid = threadIdx.x, l = tid & 63, w = tid >> 6;
    const int wm = w & 1, wn = w >> 1;
    const int b = blockIdx.y;
    int it, jt; pair_from_p(blockIdx.x, it, jt);
    const long base = (long)b * Tn * HSn;

    f32x4 acc[4][4];
    score_tile_mfma(Khi, Klo, Qhi, Qlo, base, it * 128, jt * 128, Abuf, Bbuf, acc, tid);

    const int rquad = (l >> 4) * 4, col = l & 15;
    #pragma unroll
    for (int nt = 0; nt < 4; ++nt) {
        const int j = jt * 128 + wn * 64 + nt * 16 + col;
        float m = NEG_BIG;
        #pragma unroll
        for (int mt = 0; mt < 4; ++mt)
            #pragma unroll
            for (int r = 0; r < 4; ++r) {
                const int i = it * 128 + wm * 64 + mt * 16 + rquad + r;
                const float sv = (i >= j) ? acc[mt][nt][r] * SCALE : NEG_BIG;
                acc[mt][nt][r] = sv;
                m = fmaxf(m, sv);
            }
        m = fmaxf(m, __shfl_xor(m, 16));
        m = fmaxf(m, __shfl_xor(m, 32));
        float d = 0.f;
        #pragma unroll
        for (int mt = 0; mt < 4; ++mt)
            #pragma unroll
            for (int r = 0; r < 4; ++r)
                d += __expf(acc[mt][nt][r] - m);
        d += __shfl_xor(d, 16);
        d += __shfl_xor(d, 32);
        if (l < 16) {
            redm[wm][wn * 64 + nt * 16 + l] = m;
            redd[wm][wn * 64 + nt * 16 + l] = d;
        }
    }
    __syncthreads();
    if (tid < 128) {
        const float m0 = redm[0][tid], m1 = redm[1][tid];
        const float d0 = redd[0][tid], d1 = redd[1][tid];
        const float M = fmaxf(m0, m1);
        float D = d0 * __expf(m0 - M) + d1 * __expf(m1 - M);
        const float Mb = bf16_rn_f(M);
        D *= __expf(M - Mb);      // rebase to the rounded max we will store
        const long idx = ((long)b * NPAIR + blockIdx.x) * 128 + tid;
        Pm[idx] = (u16)(__float_as_uint(Mb) >> 16);
        Pd[idx] = bf16_rn(D);
    }
}

// ---------------------------------------------------------------------------
// Kernel 2b: merge partials over i-tiles -> Ms, Rd.
// ---------------------------------------------------------------------------
__global__ __launch_bounds__(128) void stats2_kernel(
    const u16* __restrict__ Pm, const u16* __restrict__ Pd,
    float* __restrict__ Ms, float* __restrict__ Rd)
{
    const int b = blockIdx.y, jt = blockIdx.x, jl = threadIdx.x;  // 128 threads
    float M = NEG_BIG, D = 0.f;
    for (int it = jt; it < NT; ++it) {
        const int p = it * (it + 1) / 2 + jt;
        const long idx = ((long)b * NPAIR + p) * 128 + jl;
        const float m = __uint_as_float((u32)Pm[idx] << 16);
        const float d = __uint_as_float((u32)Pd[idx] << 16);
        const float Mn = fmaxf(M, m);
        D = D * __expf(M - Mn) + d * __expf(m - Mn);
        M = Mn;
    }
    Ms[(long)b * Tn + jt * 128 + jl] = M;
    Rd[(long)b * Tn + jt * 128 + jl] = 1.f / D;
}

// ---------------------------------------------------------------------------
// Kernel 3: per-pair output partials (validated R3).
// ---------------------------------------------------------------------------
__global__ __launch_bounds__(256) void out_kernel(
    const u16* __restrict__ Khi, const u16* __restrict__ Klo,
    const u16* __restrict__ Qhi, const u16* __restrict__ Qlo,
    const u16* __restrict__ Vbf, const float* __restrict__ Ms,
    const float* __restrict__ Rd, float* __restrict__ Out)
{
    __shared__ u16 u_lds[34816];
    u16* Abuf = u_lds;
    u16* Bbuf = u_lds + 8192;
    u16* Pf   = u_lds;           // [128][136] bf16
    u16* Vt   = u_lds + 17408;   // [128][136] bf16 (h-major)

    const int tid = threadIdx.x, l = tid & 63, w = tid >> 6;
    const int wm = w & 1, wn = w >> 1;
    const int b = blockIdx.y;
    int it, jt; pair_from_p(blockIdx.x, it, jt);
    const long base = (long)b * Tn * HSn;

    f32x4 acc[4][4];
    score_tile_mfma(Khi, Klo, Qhi, Qlo, base, it * 128, jt * 128, Abuf, Bbuf, acc, tid);

    const int rquad = (l >> 4) * 4, col = l & 15;
    float mj[4], rj[4];
    #pragma unroll
    for (int nt = 0; nt < 4; ++nt) {
        const int j = jt * 128 + wn * 64 + nt * 16 + col;
        mj[nt] = Ms[(long)b * Tn + j];
        rj[nt] = Rd[(long)b * Tn + j];
    }
    #pragma unroll
    for (int nt = 0; nt < 4; ++nt) {
        const int j = jt * 128 + wn * 64 + nt * 16 + col;
        #pragma unroll
        for (int mt = 0; mt < 4; ++mt)
            #pragma unroll
            for (int r = 0; r < 4; ++r) {
                const int i = it * 128 + wm * 64 + mt * 16 + rquad + r;
                const float pv = (i >= j)
                    ? __expf(acc[mt][nt][r] * SCALE - mj[nt]) * rj[nt] : 0.f;
                Pf[(wm * 64 + mt * 16 + rquad + r) * 136 + wn * 64 + nt * 16 + col]
                    = bf16_rn(pv);
            }
    }

    const int lrow = l & 15, lk8 = (l >> 4) << 3;
    for (int ph = 0; ph < 2; ++ph) {
        __syncthreads();
        {
            const int jj = tid & 127, hs = (tid >> 7) * 64;
            const long vbase = ((long)b * Tn + jt * 128 + jj) * HSn + ph * 128 + hs;
            #pragma unroll
            for (int qq = 0; qq < 8; ++qq) {
                union { uint4 v; u16 s[8]; } uu;
                uu.v = *(const uint4*)(Vbf + vbase + qq * 8);
                #pragma unroll
                for (int e = 0; e < 8; ++e)
                    Vt[(hs + qq * 8 + e) * 136 + jj] = uu.s[e];
            }
        }
        __syncthreads();

        f32x4 o[4][4];
        #pragma unroll
        for (int a = 0; a < 4; ++a)
            #pragma unroll
            for (int bb = 0; bb < 4; ++bb)
                #pragma unroll
                for (int r = 0; r < 4; ++r) o[a][bb][r] = 0.f;

        #pragma unroll
        for (int kj = 0; kj < 4; ++kj) {
            bf16x8 aP[4];
            #pragma unroll
            for (int mt = 0; mt < 4; ++mt)
                aP[mt] = *(const bf16x8*)(Pf + (wm * 64 + mt * 16 + lrow) * 136 + kj * 32 + lk8);
            #pragma unroll
            for (int nt = 0; nt < 4; ++nt) {
                const bf16x8 bV = *(const bf16x8*)(Vt + (wn * 64 + nt * 16 + lrow) * 136 + kj * 32 + lk8);
                #pragma unroll
                for (int mt = 0; mt < 4; ++mt)
                    o[mt][nt] = __builtin_amdgcn_mfma_f32_16x16x32_bf16(aP[mt], bV, o[mt][nt], 0, 0, 0);
            }
        }
        #pragma unroll
        for (int mt = 0; mt < 4; ++mt)
            #pragma unroll
            for (int nt = 0; nt < 4; ++nt)
                #pragma unroll
                for (int r = 0; r < 4; ++r) {
                    const int i = it * 128 + wm * 64 + mt * 16 + rquad + r;
                    const int h = ph * 128 + wn * 64 + nt * 16 + col;
                    atomicAdd(&Out[((long)b * Tn + i) * HSn + h], o[mt][nt][r]);
                }
    }
}

extern "C" void kernel_launch(void* const* d_in, const int* in_sizes, int n_in,
                              void* d_out, int out_size, void* d_ws, size_t ws_size,
                              hipStream_t stream) {
    const float* X  = (const float*)d_in[0];
    const float* Wk = (const float*)d_in[1];
    const float* Wq = (const float*)d_in[2];
    const float* Wv = (const float*)d_in[3];

    const long nE = (long)Bn * Tn * HSn;          // 8,388,608 elements
    u16* Khi = (u16*)d_ws;
    u16* Klo = Khi + nE;
    u16* Qhi = Khi + 2 * nE;
    u16* Qlo = Khi + 3 * nE;
    u16* Vbf = Khi + 4 * nE;
    u16* Wt  = Khi + 5 * nE;                      // 6 arrays of WN (hi/lo x K,Q,V)
    u16* Pm  = Wt + 6L * WN;                      // [B][NPAIR][128] bf16
    u16* Pd  = Pm + (long)Bn * NPAIR * 128;
    float* Ms = (float*)(Pd + (long)Bn * NPAIR * 128);
    float* Rd = Ms + (long)Bn * Tn;
    // total ws ~= 91.5 MiB (< 96.6 MiB proven in R2)

    split_w_kernel<<<dim3(Cn, 3), 256, 0, stream>>>(Wk, Wq, Wv, Wt);
    projm_kernel<<<dim3((Bn * Tn) / 128, HSn / 128, 3), 256, 0, stream>>>(
        X, Wt, Khi, Klo, Qhi, Qlo, Vbf);
    stats1_kernel<<<dim3(NPAIR, Bn), 256, 0, stream>>>(Khi, Klo, Qhi, Qlo, Pm, Pd);
    stats2_kernel<<<dim3(NT, Bn), 128, 0, stream>>>(Pm, Pd, Ms, Rd);
    hipMemsetAsync(d_out, 0, (size_t)out_size * sizeof(float), stream);
    out_kernel<<<dim3(NPAIR, Bn), 256, 0, stream>>>(Khi, Klo, Qhi, Qlo, Vbf, Ms, Rd,
                                                    (float*)d_out);
}